// Round 2
// baseline (3433.146 us; speedup 1.0000x reference)
//
#include <hip/hip_runtime.h>
#include <cstdint>

using u16 = unsigned short;
using u32 = unsigned int;

typedef __bf16 bf16x8 __attribute__((ext_vector_type(8)));
typedef float f32x4 __attribute__((ext_vector_type(4)));

__device__ __forceinline__ float bf2f(u16 u) {
    u32 v = ((u32)u) << 16; float f; __builtin_memcpy(&f, &v, 4); return f;
}
__device__ __forceinline__ u16 f2bf(float f) {
    u32 u; __builtin_memcpy(&u, &f, 4);
    u32 r = (u + 0x7fffu + ((u >> 16) & 1u)) >> 16; return (u16)r;
}
__device__ __forceinline__ u32 pack2(float a, float b) {
    return (u32)f2bf(a) | ((u32)f2bf(b) << 16);
}
// generic load: buffer is fp32 (f32==true) or bf16
__device__ __forceinline__ float ldv(const void* p, size_t i, bool f32) {
    return f32 ? ((const float*)p)[i] : bf2f(((const u16*)p)[i]);
}

// ---------------------------------------------------------------------------
// dtype detect: if buffer is fp32, u16 at EVEN indices are low halves of
// floats (random mantissa bits -> random "exponent field"); if bf16, every
// u16 is a bf16 of N(0,1) (exponent near 126). Deterministic on fixed input.
// ---------------------------------------------------------------------------
__global__ void detect_k(const u16* __restrict__ x, int* __restrict__ flag) {
    if (threadIdx.x != 0 || blockIdx.x != 0) return;
    int weird = 0;
    for (int i = 0; i < 512; ++i) {
        u16 u = x[2 * i];
        int e = (u >> 7) & 0xff;
        if (e != 0 && (e < 100 || e > 140)) ++weird;
    }
    *flag = (weird > 64) ? 1 : 0;
}

// ---------------------------------------------------------------------------
// weight transpose (w [R][C] -> wt [C][R]) with dtype branch, output bf16
// ---------------------------------------------------------------------------
__global__ __launch_bounds__(256) void transp_k(const void* __restrict__ in,
                                                u16* __restrict__ outp,
                                                int R, int C,
                                                const int* __restrict__ dtf) {
    __shared__ alignas(16) u16 t[32][33];
    const bool f32 = (*dtf) != 0;
    int tx = threadIdx.x & 31, ty = threadIdx.x >> 5;
    int bx = blockIdx.x * 32, by = blockIdx.y * 32;
#pragma unroll
    for (int i = 0; i < 4; ++i)
        t[ty + i * 8][tx] = f2bf(ldv(in, (size_t)(by + ty + i * 8) * C + bx + tx, f32));
    __syncthreads();
#pragma unroll
    for (int i = 0; i < 4; ++i)
        outp[(size_t)(bx + ty + i * 8) * R + by + tx] = t[tx][ty + i * 8];
}

// ---------------------------------------------------------------------------
// LN1: per-token layernorm*g1+b1 -> lnout (native dtype). 8 tokens/block.
// ---------------------------------------------------------------------------
__global__ __launch_bounds__(512) void ln_k(const void* __restrict__ xin,
                                            const void* __restrict__ g1,
                                            const void* __restrict__ b1,
                                            void* __restrict__ lnout,
                                            const int* __restrict__ dtf) {
    const bool f32 = (*dtf) != 0;
    const int token = blockIdx.x * 8 + (threadIdx.x >> 6);
    const int l = threadIdx.x & 63;
    const size_t base = (size_t)token * 512 + l * 8;
    float v[8];
    if (f32) {
        const float4* p = (const float4*)((const float*)xin + base);
        float4 a = p[0], b = p[1];
        v[0]=a.x; v[1]=a.y; v[2]=a.z; v[3]=a.w; v[4]=b.x; v[5]=b.y; v[6]=b.z; v[7]=b.w;
    } else {
        uint4 q = *(const uint4*)((const u16*)xin + base);
        const u16* qp = (const u16*)&q;
#pragma unroll
        for (int j = 0; j < 8; ++j) v[j] = bf2f(qp[j]);
    }
    float s = 0.f, qq = 0.f;
#pragma unroll
    for (int j = 0; j < 8; ++j) { s += v[j]; qq += v[j] * v[j]; }
#pragma unroll
    for (int off = 1; off < 64; off <<= 1) {
        s += __shfl_xor(s, off); qq += __shfl_xor(qq, off);
    }
    float m = s * (1.f / 512.f);
    float var = qq * (1.f / 512.f) - m * m;
    float r = rsqrtf(var + 1e-5f);
    float o[8];
#pragma unroll
    for (int j = 0; j < 8; ++j)
        o[j] = (v[j] - m) * r * ldv(g1, l * 8 + j, f32) + ldv(b1, l * 8 + j, f32);
    if (f32) {
        float4* op = (float4*)((float*)lnout + base);
        op[0] = make_float4(o[0], o[1], o[2], o[3]);
        op[1] = make_float4(o[4], o[5], o[6], o[7]);
    } else {
        uint4 w;
        w.x = pack2(o[0], o[1]); w.y = pack2(o[2], o[3]);
        w.z = pack2(o[4], o[5]); w.w = pack2(o[6], o[7]);
        *(uint4*)((u16*)lnout + base) = w;
    }
}

// ---------------------------------------------------------------------------
// Window mix: x_mid[p] = x[p] + sum_j sw[h][p][j]*ln[j] + sb.  In-place on
// the ln buffer (window token rows are touched only by their own block;
// all 49 ln rows staged to LDS before any write).
// ---------------------------------------------------------------------------
__global__ __launch_bounds__(512) void mix_k(const void* __restrict__ xin,
                                             const void* __restrict__ lnb,
                                             const void* __restrict__ sw,
                                             const void* __restrict__ sb,
                                             void* __restrict__ outp,
                                             const int* __restrict__ dtf) {
    __shared__ alignas(16) u16 raw[49 * 512];
    __shared__ int toks[49];
    const bool f32 = (*dtf) != 0;
    const int tid = threadIdx.x;
    const int wid = blockIdx.x;
    const int b = wid / 81, rem = wid % 81;
    const int wy = rem / 9, wx = rem % 9;

    if (tid < 49) {
        int py = tid / 7, px = tid % 7;
        int y = wy * 7 + py - 4, x = wx * 7 + px - 4;  // PT=PL=4
        toks[tid] = ((unsigned)y < 56u && (unsigned)x < 56u)
                        ? (b * 3136 + y * 56 + x) : -1;
    }
    __syncthreads();

    // stage ln rows (zeros at padded positions), as bf16
    for (int idx = tid; idx < 49 * 64; idx += 512) {
        int p = idx >> 6, uu = idx & 63;
        int tk = toks[p];
        uint4 w = make_uint4(0, 0, 0, 0);
        if (tk >= 0) {
            size_t base = (size_t)tk * 512 + uu * 8;
            if (f32) {
                const float4* s0 = (const float4*)((const float*)lnb + base);
                float4 a = s0[0], bb = s0[1];
                w.x = pack2(a.x, a.y);  w.y = pack2(a.z, a.w);
                w.z = pack2(bb.x, bb.y); w.w = pack2(bb.z, bb.w);
            } else {
                w = *(const uint4*)((const u16*)lnb + base);
            }
        }
        *(uint4*)(raw + p * 512 + uu * 8) = w;
    }
    __syncthreads();

    const int c = tid;
    const int h = c >> 5;
    float lnv[49];
#pragma unroll
    for (int j = 0; j < 49; ++j) lnv[j] = bf2f(raw[j * 512 + c]);

    const size_t swbase = (size_t)h * 2401;
    for (int p = 0; p < 49; ++p) {
        int tk = toks[p];
        if (tk < 0) continue;
        float acc = 0.f;
#pragma unroll
        for (int j = 0; j < 49; ++j)
            acc += ldv(sw, swbase + p * 49 + j, f32) * lnv[j];
        float o = acc + ldv(sb, h * 49 + p, f32) + ldv(xin, (size_t)tk * 512 + c, f32);
        if (f32) ((float*)outp)[(size_t)tk * 512 + c] = o;
        else     ((u16*)outp)[(size_t)tk * 512 + c] = f2bf(o);
    }
}

// ---------------------------------------------------------------------------
// LN2 stats (mean, rstd) from x_mid (native dtype). 8 tokens/block.
// ---------------------------------------------------------------------------
__global__ __launch_bounds__(512) void stats_k(const void* __restrict__ xm,
                                               float2* __restrict__ st,
                                               const int* __restrict__ dtf) {
    const bool f32 = (*dtf) != 0;
    const int token = blockIdx.x * 8 + (threadIdx.x >> 6);
    const int l = threadIdx.x & 63;
    const size_t base = (size_t)token * 512 + l * 8;
    float v[8];
    if (f32) {
        const float4* p = (const float4*)((const float*)xm + base);
        float4 a = p[0], b = p[1];
        v[0]=a.x; v[1]=a.y; v[2]=a.z; v[3]=a.w; v[4]=b.x; v[5]=b.y; v[6]=b.z; v[7]=b.w;
    } else {
        uint4 q = *(const uint4*)((const u16*)xm + base);
        const u16* qp = (const u16*)&q;
#pragma unroll
        for (int j = 0; j < 8; ++j) v[j] = bf2f(qp[j]);
    }
    float s = 0.f, qq = 0.f;
#pragma unroll
    for (int j = 0; j < 8; ++j) { s += v[j]; qq += v[j] * v[j]; }
#pragma unroll
    for (int off = 1; off < 64; off <<= 1) {
        s += __shfl_xor(s, off); qq += __shfl_xor(qq, off);
    }
    if (l == 0) {
        float m = s * (1.f / 512.f);
        float var = qq * (1.f / 512.f) - m * m;
        st[token] = make_float2(m, rsqrtf(var + 1e-5f));
    }
}

// ---------------------------------------------------------------------------
// MFMA GEMM: C[M][ND] = A[M][KD] @ Wt[ND][KD]^T, 128x128 tile, BK=64,
// 4 waves (2x2), each 64x64 via 4x4 frags of 16x16x32 bf16 MFMA.
// EPI==0: A = LN2(x_mid) fused via stats; epilogue bias+GELU -> hid (bf16)
// EPI==1: A = hid (bf16); epilogue bias + residual RMW on Out (native)
// ---------------------------------------------------------------------------
template <int KD, int ND, int EPI>
__global__ __launch_bounds__(256) void gemm_k(const void* __restrict__ A,
                                              const float2* __restrict__ stats,
                                              const void* __restrict__ G,
                                              const void* __restrict__ Bv,
                                              const u16* __restrict__ Wt,
                                              const void* __restrict__ bias,
                                              void* __restrict__ Out, int row0,
                                              const int* __restrict__ dtf) {
    __shared__ alignas(16) u16 As[128 * 64];
    __shared__ alignas(16) u16 Bs[128 * 64];
    const bool f32 = (*dtf) != 0;
    const int tid = threadIdx.x;
    const int l = tid & 63, wv = tid >> 6;
    const int wm = wv >> 1, wn = wv & 1;
    const int lr = l & 15, lk = l >> 4;
    const int bm = blockIdx.y, bn = blockIdx.x;

    f32x4 acc[4][4] = {};

    for (int ks = 0; ks < KD; ks += 64) {
        // stage A and B tiles: logical chunk (r, c) -> physical chunk c^(r&7)
#pragma unroll
        for (int i = 0; i < 4; ++i) {
            int q = tid + i * 256;
            int r = q >> 3, cc = q & 7;
            int pr = r * 8 + (cc ^ (r & 7));
            if (EPI == 0) {
                int grow = row0 + bm * 128 + r;
                float xv[8];
                if (f32) {
                    const float4* p0 = (const float4*)((const float*)A + (size_t)grow * KD + ks + cc * 8);
                    float4 a = p0[0], bq = p0[1];
                    xv[0]=a.x; xv[1]=a.y; xv[2]=a.z; xv[3]=a.w;
                    xv[4]=bq.x; xv[5]=bq.y; xv[6]=bq.z; xv[7]=bq.w;
                } else {
                    uint4 rv = *(const uint4*)((const u16*)A + (size_t)grow * KD + ks + cc * 8);
                    const u16* rp = (const u16*)&rv;
#pragma unroll
                    for (int j = 0; j < 8; ++j) xv[j] = bf2f(rp[j]);
                }
                float2 stv = stats[grow];
                float o[8];
#pragma unroll
                for (int j = 0; j < 8; ++j) {
                    float nv = (xv[j] - stv.x) * stv.y;
                    o[j] = nv * ldv(G, ks + cc * 8 + j, f32) + ldv(Bv, ks + cc * 8 + j, f32);
                }
                uint4 w;
                w.x = pack2(o[0], o[1]); w.y = pack2(o[2], o[3]);
                w.z = pack2(o[4], o[5]); w.w = pack2(o[6], o[7]);
                reinterpret_cast<uint4*>(As)[pr] = w;
            } else {
                int lrow = bm * 128 + r;
                uint4 rv = *(const uint4*)((const u16*)A + (size_t)lrow * KD + ks + cc * 8);
                reinterpret_cast<uint4*>(As)[pr] = rv;
            }
            int nrow = bn * 128 + r;
            uint4 wv4 = *(const uint4*)(Wt + (size_t)nrow * KD + ks + cc * 8);
            reinterpret_cast<uint4*>(Bs)[pr] = wv4;
        }
        __syncthreads();
#pragma unroll
        for (int kk = 0; kk < 2; ++kk) {
            bf16x8 af[4], bfr[4];
#pragma unroll
            for (int f = 0; f < 4; ++f) {
                int ra = wm * 64 + f * 16 + lr;
                af[f] = *reinterpret_cast<const bf16x8*>(
                    As + ra * 64 + (((kk * 4 + lk) ^ (ra & 7)) * 8));
                int rb = wn * 64 + f * 16 + lr;
                bfr[f] = *reinterpret_cast<const bf16x8*>(
                    Bs + rb * 64 + (((kk * 4 + lk) ^ (rb & 7)) * 8));
            }
#pragma unroll
            for (int fi = 0; fi < 4; ++fi)
#pragma unroll
                for (int fj = 0; fj < 4; ++fj)
                    acc[fi][fj] = __builtin_amdgcn_mfma_f32_16x16x32_bf16(
                        af[fi], bfr[fj], acc[fi][fj], 0, 0, 0);
        }
        __syncthreads();
    }

    // epilogue: D row = (lane>>4)*4 + reg, col = lane&15
#pragma unroll
    for (int fi = 0; fi < 4; ++fi) {
#pragma unroll
        for (int fj = 0; fj < 4; ++fj) {
#pragma unroll
            for (int rr = 0; rr < 4; ++rr) {
                int mrow = bm * 128 + wm * 64 + fi * 16 + lk * 4 + rr;
                int ncol = bn * 128 + wn * 64 + fj * 16 + lr;
                float v = acc[fi][fj][rr] + ldv(bias, ncol, f32);
                if (EPI == 0) {
                    float ge = 0.5f * v * (1.0f + erff(v * 0.70710678118654752f));
                    ((u16*)Out)[(size_t)mrow * ND + ncol] = f2bf(ge);
                } else {
                    size_t oi = (size_t)(row0 + mrow) * ND + ncol;
                    if (f32) {
                        float* Of = (float*)Out;
                        Of[oi] = Of[oi] + v;
                    } else {
                        u16* O16 = (u16*)Out;
                        O16[oi] = f2bf(bf2f(O16[oi]) + v);
                    }
                }
            }
        }
    }
}

// ---------------------------------------------------------------------------
extern "C" void kernel_launch(void* const* d_in, const int* in_sizes, int n_in,
                              void* d_out, int out_size, void* d_ws, size_t ws_size,
                              hipStream_t stream) {
    const void* x   = d_in[0];
    const void* g1  = d_in[1];
    const void* b1  = d_in[2];
    const void* sw  = d_in[3];
    const void* sb  = d_in[4];
    const void* g2  = d_in[5];
    const void* b2  = d_in[6];
    const void* w1  = d_in[7];
    const void* bb1 = d_in[8];
    const void* w2  = d_in[9];
    const void* bb2 = d_in[10];

    char* ws = (char*)d_ws;
    float2* stats = (float2*)ws;                          // 100352*8 = 802816 B
    int* dtf = (int*)(ws + 802816);                       // 4 B (pad to 256)
    u16* w1t = (u16*)(ws + 803072);                       // [2048][512]  2 MB
    u16* w2t = (u16*)(ws + 803072 + 2097152);             // [512][2048]  2 MB
    size_t hid_off = 803072 + 2u * 2097152;               // 4,997,376
    u16* hid = (u16*)(ws + hid_off);                      // chunked [rows][2048]

    long avail = (long)ws_size - (long)hid_off;
    long maxT = avail / (128 * 2048 * 2);
    int chunkT = (int)(maxT < 1 ? 1 : (maxT > 784 ? 784 : maxT));

    detect_k<<<1, 64, 0, stream>>>((const u16*)x, dtf);
    transp_k<<<dim3(64, 16), 256, 0, stream>>>(w1, w1t, 512, 2048, dtf);
    transp_k<<<dim3(16, 64), 256, 0, stream>>>(w2, w2t, 2048, 512, dtf);
    ln_k<<<12544, 512, 0, stream>>>(x, g1, b1, d_out, dtf);
    mix_k<<<2592, 512, 0, stream>>>(x, d_out, sw, sb, d_out, dtf);
    stats_k<<<12544, 512, 0, stream>>>(d_out, stats, dtf);
    for (int t0 = 0; t0 < 784; t0 += chunkT) {
        int nt = (784 - t0) < chunkT ? (784 - t0) : chunkT;
        gemm_k<512, 2048, 0><<<dim3(16, nt), 256, 0, stream>>>(
            d_out, stats, g2, b2, w1t, bb1, hid, t0 * 128, dtf);
        gemm_k<2048, 512, 1><<<dim3(4, nt), 256, 0, stream>>>(
            hid, stats, g2, b2, w2t, bb2, d_out, t0 * 128, dtf);
    }
}

// Round 6
// 2584.504 us; speedup vs baseline: 1.3284x; 1.3284x over previous
//
#include <hip/hip_runtime.h>
#include <cstdint>

using u16 = unsigned short;
using u32 = unsigned int;

typedef __bf16 bf16x8 __attribute__((ext_vector_type(8)));
typedef float f32x4 __attribute__((ext_vector_type(4)));

__device__ __forceinline__ float bf2f(u16 u) {
    u32 v = ((u32)u) << 16; float f; __builtin_memcpy(&f, &v, 4); return f;
}
__device__ __forceinline__ u16 f2bf(float f) {
    u32 u; __builtin_memcpy(&u, &f, 4);
    u32 r = (u + 0x7fffu + ((u >> 16) & 1u)) >> 16; return (u16)r;
}
__device__ __forceinline__ u32 pack2(float a, float b) {
    return (u32)f2bf(a) | ((u32)f2bf(b) << 16);
}
// bijective chunked XCD swizzle (m204)
__device__ __forceinline__ int xcd_swz(int orig, int nwg) {
    int q = nwg >> 3, r8 = nwg & 7;
    int xcd = orig & 7, slot = orig >> 3;
    return (xcd < r8 ? xcd * (q + 1) : r8 * (q + 1) + (xcd - r8) * q) + slot;
}

// ---------------------------------------------------------------------------
// weight transpose: w [R][C] fp32 -> wt [C][R] bf16
// ---------------------------------------------------------------------------
__global__ __launch_bounds__(256) void transp_k(const float* __restrict__ in,
                                                u16* __restrict__ outp,
                                                int R, int C) {
    __shared__ alignas(16) u16 t[32][33];
    int tx = threadIdx.x & 31, ty = threadIdx.x >> 5;
    int bx = blockIdx.x * 32, by = blockIdx.y * 32;
#pragma unroll
    for (int i = 0; i < 4; ++i)
        t[ty + i * 8][tx] = f2bf(in[(size_t)(by + ty + i * 8) * C + bx + tx]);
    __syncthreads();
#pragma unroll
    for (int i = 0; i < 4; ++i)
        outp[(size_t)(bx + ty + i * 8) * R + by + tx] = t[tx][ty + i * 8];
}

// ---------------------------------------------------------------------------
// LN1: fp32 in -> fp32 ln(x)*g1+b1 into d_out (temp). 8 tokens/block.
// ---------------------------------------------------------------------------
__global__ __launch_bounds__(512) void ln_k(const float* __restrict__ xin,
                                            const float* __restrict__ g1,
                                            const float* __restrict__ b1,
                                            float* __restrict__ lnout) {
    const int token = blockIdx.x * 8 + (threadIdx.x >> 6);
    const int l = threadIdx.x & 63;
    const size_t base = (size_t)token * 512 + l * 8;
    const float4* p = (const float4*)(xin + base);
    float4 a = p[0], b = p[1];
    float v[8] = {a.x, a.y, a.z, a.w, b.x, b.y, b.z, b.w};
    float s = 0.f, qq = 0.f;
#pragma unroll
    for (int j = 0; j < 8; ++j) { s += v[j]; qq += v[j] * v[j]; }
#pragma unroll
    for (int off = 1; off < 64; off <<= 1) {
        s += __shfl_xor(s, off); qq += __shfl_xor(qq, off);
    }
    float m = s * (1.f / 512.f);
    float var = qq * (1.f / 512.f) - m * m;
    float r = rsqrtf(var + 1e-5f);
    float o[8];
#pragma unroll
    for (int j = 0; j < 8; ++j)
        o[j] = (v[j] - m) * r * g1[l * 8 + j] + b1[l * 8 + j];
    float4* op = (float4*)(lnout + base);
    op[0] = make_float4(o[0], o[1], o[2], o[3]);
    op[1] = make_float4(o[4], o[5], o[6], o[7]);
}

// ---------------------------------------------------------------------------
// Window mix: x_mid[p] = x[p] + sum_j sw[h][p][j]*ln[j] + sb. In-place on
// d_out (token-partition: each token read+written by exactly one block,
// all 49 ln rows staged to LDS before any write).
// ---------------------------------------------------------------------------
__global__ __launch_bounds__(512) void mix_k(const float* __restrict__ xin,
                                             const float* __restrict__ lnb,
                                             const float* __restrict__ sw,
                                             const float* __restrict__ sb,
                                             float* __restrict__ outp) {
    __shared__ alignas(16) u16 raw[49 * 512];
    __shared__ int toks[49];
    const int tid = threadIdx.x;
    const int wid = blockIdx.x;
    const int b = wid / 81, rem = wid % 81;
    const int wy = rem / 9, wx = rem % 9;

    if (tid < 49) {
        int py = tid / 7, px = tid % 7;
        int y = wy * 7 + py - 4, x = wx * 7 + px - 4;  // PT=PL=4
        toks[tid] = ((unsigned)y < 56u && (unsigned)x < 56u)
                        ? (b * 3136 + y * 56 + x) : -1;
    }
    __syncthreads();

    for (int idx = tid; idx < 49 * 64; idx += 512) {
        int p = idx >> 6, uu = idx & 63;
        int tk = toks[p];
        uint4 w = make_uint4(0, 0, 0, 0);
        if (tk >= 0) {
            const float4* s0 = (const float4*)(lnb + (size_t)tk * 512 + uu * 8);
            float4 a = s0[0], bb = s0[1];
            w.x = pack2(a.x, a.y);  w.y = pack2(a.z, a.w);
            w.z = pack2(bb.x, bb.y); w.w = pack2(bb.z, bb.w);
        }
        *(uint4*)(raw + p * 512 + uu * 8) = w;
    }
    __syncthreads();

    const int c = tid;
    const int h = c >> 5;
    float lnv[49];
#pragma unroll
    for (int j = 0; j < 49; ++j) lnv[j] = bf2f(raw[j * 512 + c]);

    const size_t swbase = (size_t)h * 2401;
    for (int p = 0; p < 49; ++p) {
        int tk = toks[p];
        if (tk < 0) continue;
        float acc = 0.f;
#pragma unroll
        for (int j = 0; j < 49; ++j)
            acc += sw[swbase + p * 49 + j] * lnv[j];
        float o = acc + sb[h * 49 + p] + xin[(size_t)tk * 512 + c];
        outp[(size_t)tk * 512 + c] = o;
    }
}

// ---------------------------------------------------------------------------
// LN2 stats (mean, rstd) from x_mid fp32. 8 tokens/block.
// ---------------------------------------------------------------------------
__global__ __launch_bounds__(512) void stats_k(const float* __restrict__ xm,
                                               float2* __restrict__ st) {
    const int token = blockIdx.x * 8 + (threadIdx.x >> 6);
    const int l = threadIdx.x & 63;
    const size_t base = (size_t)token * 512 + l * 8;
    const float4* p = (const float4*)(xm + base);
    float4 a = p[0], b = p[1];
    float v[8] = {a.x, a.y, a.z, a.w, b.x, b.y, b.z, b.w};
    float s = 0.f, qq = 0.f;
#pragma unroll
    for (int j = 0; j < 8; ++j) { s += v[j]; qq += v[j] * v[j]; }
#pragma unroll
    for (int off = 1; off < 64; off <<= 1) {
        s += __shfl_xor(s, off); qq += __shfl_xor(qq, off);
    }
    if (l == 0) {
        float m = s * (1.f / 512.f);
        float var = qq * (1.f / 512.f) - m * m;
        st[token] = make_float2(m, rsqrtf(var + 1e-5f));
    }
}

// ---------------------------------------------------------------------------
// GEMM1: hid[bf16] = GELU(LN2(x_mid[f32]) @ W1t[bf16] + bb1), 128x128 tile,
// BK=64, 4 waves (2x2), T14 reg-prefetch, XCD-swizzled 1D grid.
// ---------------------------------------------------------------------------
__global__ __launch_bounds__(256) void gemm1_k(const float* __restrict__ A,
                                               const float2* __restrict__ stats,
                                               const float* __restrict__ G,
                                               const float* __restrict__ Bv,
                                               const u16* __restrict__ Wt,
                                               const float* __restrict__ bias,
                                               u16* __restrict__ Out, int row0) {
    constexpr int KD = 512, ND = 2048;
    __shared__ alignas(16) u16 As[128 * 64];
    __shared__ alignas(16) u16 Bs[128 * 64];
    const int tid = threadIdx.x;
    const int l = tid & 63, w = tid >> 6;
    const int wm = w >> 1, wn = w & 1;
    const int lr = l & 15, lk = l >> 4;

    const int wg = xcd_swz(blockIdx.x, gridDim.x);
    const int bm = wg >> 4, bn = wg & 15;

    int pr_[4], gc_[4];
    const float* Ap[4]; const u16* Bp[4];
    float2 st_[4];
#pragma unroll
    for (int i = 0; i < 4; ++i) {
        int q = tid + i * 256;
        int r = q >> 3, cc = q & 7;
        pr_[i] = r * 8 + (cc ^ (r & 7));
        gc_[i] = cc * 8;
        int arow = row0 + bm * 128 + r;
        Ap[i] = A + (size_t)arow * KD + cc * 8;
        Bp[i] = Wt + (size_t)(bn * 128 + r) * KD + cc * 8;
        st_[i] = stats[arow];
    }

    float4 raA[4][2]; uint4 rb4[4];
#pragma unroll
    for (int i = 0; i < 4; ++i) {
        raA[i][0] = *(const float4*)Ap[i];
        raA[i][1] = *(const float4*)(Ap[i] + 4);
        rb4[i] = *(const uint4*)Bp[i];
    }

    f32x4 acc[4][4] = {};

    for (int ks = 0; ks < KD; ks += 64) {
        // stage tile ks from registers with fused LN2
#pragma unroll
        for (int i = 0; i < 4; ++i) {
            float xv[8] = {raA[i][0].x, raA[i][0].y, raA[i][0].z, raA[i][0].w,
                           raA[i][1].x, raA[i][1].y, raA[i][1].z, raA[i][1].w};
            float o[8];
#pragma unroll
            for (int j = 0; j < 8; ++j) {
                float nv = (xv[j] - st_[i].x) * st_[i].y;
                o[j] = nv * G[ks + gc_[i] + j] + Bv[ks + gc_[i] + j];
            }
            uint4 wv;
            wv.x = pack2(o[0], o[1]); wv.y = pack2(o[2], o[3]);
            wv.z = pack2(o[4], o[5]); wv.w = pack2(o[6], o[7]);
            reinterpret_cast<uint4*>(As)[pr_[i]] = wv;
            reinterpret_cast<uint4*>(Bs)[pr_[i]] = rb4[i];
        }
        __syncthreads();
        // T14: prefetch tile ks+64 while MFMA runs
        if (ks + 64 < KD) {
#pragma unroll
            for (int i = 0; i < 4; ++i) {
                raA[i][0] = *(const float4*)(Ap[i] + ks + 64);
                raA[i][1] = *(const float4*)(Ap[i] + ks + 68);
                rb4[i] = *(const uint4*)(Bp[i] + ks + 64);
            }
        }
#pragma unroll
        for (int kk = 0; kk < 2; ++kk) {
            bf16x8 af[4], bfr[4];
#pragma unroll
            for (int f = 0; f < 4; ++f) {
                int ra = wm * 64 + f * 16 + lr;
                af[f] = *reinterpret_cast<const bf16x8*>(
                    As + ra * 64 + (((kk * 4 + lk) ^ (ra & 7)) * 8));
                int rb = wn * 64 + f * 16 + lr;
                bfr[f] = *reinterpret_cast<const bf16x8*>(
                    Bs + rb * 64 + (((kk * 4 + lk) ^ (rb & 7)) * 8));
            }
#pragma unroll
            for (int fi = 0; fi < 4; ++fi)
#pragma unroll
                for (int fj = 0; fj < 4; ++fj)
                    acc[fi][fj] = __builtin_amdgcn_mfma_f32_16x16x32_bf16(
                        af[fi], bfr[fj], acc[fi][fj], 0, 0, 0);
        }
        __syncthreads();
    }

    // epilogue: bias + GELU -> hid (bf16). D row=(lane>>4)*4+reg, col=lane&15
#pragma unroll
    for (int fi = 0; fi < 4; ++fi) {
#pragma unroll
        for (int fj = 0; fj < 4; ++fj) {
#pragma unroll
            for (int rr = 0; rr < 4; ++rr) {
                int mrow = bm * 128 + wm * 64 + fi * 16 + lk * 4 + rr;
                int ncol = bn * 128 + wn * 64 + fj * 16 + lr;
                float v = acc[fi][fj][rr] + bias[ncol];
                float ge = 0.5f * v * (1.0f + erff(v * 0.70710678118654752f));
                Out[(size_t)mrow * ND + ncol] = f2bf(ge);
            }
        }
    }
}

// ---------------------------------------------------------------------------
// GEMM2: d_out[f32] += hid[bf16] @ W2t[bf16] + bb2. 128x128 tile, BK=64,
// 4 waves, T14 reg-prefetch, XCD-swizzled 1D grid.
// ---------------------------------------------------------------------------
__global__ __launch_bounds__(256) void gemm2_k(const u16* __restrict__ A,
                                               const u16* __restrict__ Wt,
                                               const float* __restrict__ bias,
                                               float* __restrict__ Out, int row0) {
    constexpr int KD = 2048, ND = 512;
    __shared__ alignas(16) u16 As[128 * 64];
    __shared__ alignas(16) u16 Bs[128 * 64];
    const int tid = threadIdx.x;
    const int l = tid & 63, w = tid >> 6;
    const int wm = w >> 1, wn = w & 1;
    const int lr = l & 15, lk = l >> 4;

    const int wg = xcd_swz(blockIdx.x, gridDim.x);
    const int bm = wg >> 2, bn = wg & 3;

    int pr_[4];
    const u16* Ap[4]; const u16* Bp[4];
#pragma unroll
    for (int i = 0; i < 4; ++i) {
        int q = tid + i * 256;
        int r = q >> 3, cc = q & 7;
        pr_[i] = r * 8 + (cc ^ (r & 7));
        Ap[i] = A + (size_t)(bm * 128 + r) * KD + cc * 8;
        Bp[i] = Wt + (size_t)(bn * 128 + r) * KD + cc * 8;
    }

    uint4 ra4[4], rb4[4];
#pragma unroll
    for (int i = 0; i < 4; ++i) {
        ra4[i] = *(const uint4*)Ap[i];
        rb4[i] = *(const uint4*)Bp[i];
    }

    f32x4 acc[4][4] = {};

    for (int ks = 0; ks < KD; ks += 64) {
#pragma unroll
        for (int i = 0; i < 4; ++i) {
            reinterpret_cast<uint4*>(As)[pr_[i]] = ra4[i];
            reinterpret_cast<uint4*>(Bs)[pr_[i]] = rb4[i];
        }
        __syncthreads();
        if (ks + 64 < KD) {
#pragma unroll
            for (int i = 0; i < 4; ++i) {
                ra4[i] = *(const uint4*)(Ap[i] + ks + 64);
                rb4[i] = *(const uint4*)(Bp[i] + ks + 64);
            }
        }
#pragma unroll
        for (int kk = 0; kk < 2; ++kk) {
            bf16x8 af[4], bfr[4];
#pragma unroll
            for (int f = 0; f < 4; ++f) {
                int ra = wm * 64 + f * 16 + lr;
                af[f] = *reinterpret_cast<const bf16x8*>(
                    As + ra * 64 + (((kk * 4 + lk) ^ (ra & 7)) * 8));
                int rb = wn * 64 + f * 16 + lr;
                bfr[f] = *reinterpret_cast<const bf16x8*>(
                    Bs + rb * 64 + (((kk * 4 + lk) ^ (rb & 7)) * 8));
            }
#pragma unroll
            for (int fi = 0; fi < 4; ++fi)
#pragma unroll
                for (int fj = 0; fj < 4; ++fj)
                    acc[fi][fj] = __builtin_amdgcn_mfma_f32_16x16x32_bf16(
                        af[fi], bfr[fj], acc[fi][fj], 0, 0, 0);
        }
        __syncthreads();
    }

    // epilogue: bias + residual RMW on f32 d_out
#pragma unroll
    for (int fi = 0; fi < 4; ++fi) {
#pragma unroll
        for (int fj = 0; fj < 4; ++fj) {
#pragma unroll
            for (int rr = 0; rr < 4; ++rr) {
                int mrow = bm * 128 + wm * 64 + fi * 16 + lk * 4 + rr;
                int ncol = bn * 128 + wn * 64 + fj * 16 + lr;
                float v = acc[fi][fj][rr] + bias[ncol];
                size_t oi = (size_t)(row0 + mrow) * ND + ncol;
                Out[oi] = Out[oi] + v;
            }
        }
    }
}

// ---------------------------------------------------------------------------
extern "C" void kernel_launch(void* const* d_in, const int* in_sizes, int n_in,
                              void* d_out, int out_size, void* d_ws, size_t ws_size,
                              hipStream_t stream) {
    const float* x   = (const float*)d_in[0];
    const float* g1  = (const float*)d_in[1];
    const float* b1  = (const float*)d_in[2];
    const float* sw  = (const float*)d_in[3];
    const float* sb  = (const float*)d_in[4];
    const float* g2  = (const float*)d_in[5];
    const float* b2  = (const float*)d_in[6];
    const float* w1  = (const float*)d_in[7];
    const float* bb1 = (const float*)d_in[8];
    const float* w2  = (const float*)d_in[9];
    const float* bb2 = (const float*)d_in[10];
    float* out = (float*)d_out;

    char* ws = (char*)d_ws;
    float2* stats = (float2*)ws;                          // 802816 B
    u16* w1t = (u16*)(ws + 802816);                       // [2048][512]  2 MB
    u16* w2t = (u16*)(ws + 802816 + 2097152);             // [512][2048]  2 MB
    size_t hid_off = 802816 + 2u * 2097152;               // 4,997,120
    u16* hid = (u16*)(ws + hid_off);                      // chunked [rows][2048]

    long avail = (long)ws_size - (long)hid_off;
    long maxT = avail / (128 * 2048 * 2);
    int chunkT = (int)(maxT < 1 ? 1 : (maxT > 784 ? 784 : maxT));

    transp_k<<<dim3(64, 16), 256, 0, stream>>>(w1, w1t, 512, 2048);
    transp_k<<<dim3(16, 64), 256, 0, stream>>>(w2, w2t, 2048, 512);
    ln_k<<<12544, 512, 0, stream>>>(x, g1, b1, out);
    mix_k<<<2592, 512, 0, stream>>>(x, out, sw, sb, out);
    stats_k<<<12544, 512, 0, stream>>>(out, stats);
    for (int t0 = 0; t0 < 784; t0 += chunkT) {
        int nt = (784 - t0) < chunkT ? (784 - t0) : chunkT;
        gemm1_k<<<nt * 16, 256, 0, stream>>>(
            out, stats, g2, b2, w1t, bb1, hid, t0 * 128);
        gemm2_k<<<nt * 4, 256, 0, stream>>>(
            hid, w2t, bb2, out, t0 * 128);
    }
}

// Round 8
// 2502.441 us; speedup vs baseline: 1.3719x; 1.0328x over previous
//
#include <hip/hip_runtime.h>
#include <cstdint>

using u16 = unsigned short;
using u32 = unsigned int;

typedef __bf16 bf16x8 __attribute__((ext_vector_type(8)));
typedef float f32x4 __attribute__((ext_vector_type(4)));

__device__ __forceinline__ float bf2f(u16 u) {
    u32 v = ((u32)u) << 16; float f; __builtin_memcpy(&f, &v, 4); return f;
}
__device__ __forceinline__ u16 f2bf(float f) {
    u32 u; __builtin_memcpy(&u, &f, 4);
    u32 r = (u + 0x7fffu + ((u >> 16) & 1u)) >> 16; return (u16)r;
}
__device__ __forceinline__ u32 pack2(float a, float b) {
    return (u32)f2bf(a) | ((u32)f2bf(b) << 16);
}
// bijective chunked XCD swizzle (m204)
__device__ __forceinline__ int xcd_swz(int orig, int nwg) {
    int q = nwg >> 3, r8 = nwg & 7;
    int xcd = orig & 7, slot = orig >> 3;
    return (xcd < r8 ? xcd * (q + 1) : r8 * (q + 1) + (xcd - r8) * q) + slot;
}

// ---------------------------------------------------------------------------
// weight transpose: w [R][C] fp32 -> wt [C][R] bf16
// ---------------------------------------------------------------------------
__global__ __launch_bounds__(256) void transp_k(const float* __restrict__ in,
                                                u16* __restrict__ outp,
                                                int R, int C) {
    __shared__ alignas(16) u16 t[32][33];
    int tx = threadIdx.x & 31, ty = threadIdx.x >> 5;
    int bx = blockIdx.x * 32, by = blockIdx.y * 32;
#pragma unroll
    for (int i = 0; i < 4; ++i)
        t[ty + i * 8][tx] = f2bf(in[(size_t)(by + ty + i * 8) * C + bx + tx]);
    __syncthreads();
#pragma unroll
    for (int i = 0; i < 4; ++i)
        outp[(size_t)(bx + ty + i * 8) * R + by + tx] = t[tx][ty + i * 8];
}

// ---------------------------------------------------------------------------
// LN1: fp32 in -> fp32 ln(x)*g1+b1 into d_out (temp). 8 tokens/block.
// ---------------------------------------------------------------------------
__global__ __launch_bounds__(512) void ln_k(const float* __restrict__ xin,
                                            const float* __restrict__ g1,
                                            const float* __restrict__ b1,
                                            float* __restrict__ lnout) {
    const int token = blockIdx.x * 8 + (threadIdx.x >> 6);
    const int l = threadIdx.x & 63;
    const size_t base = (size_t)token * 512 + l * 8;
    const float4* p = (const float4*)(xin + base);
    float4 a = p[0], b = p[1];
    float v[8] = {a.x, a.y, a.z, a.w, b.x, b.y, b.z, b.w};
    float s = 0.f, qq = 0.f;
#pragma unroll
    for (int j = 0; j < 8; ++j) { s += v[j]; qq += v[j] * v[j]; }
#pragma unroll
    for (int off = 1; off < 64; off <<= 1) {
        s += __shfl_xor(s, off); qq += __shfl_xor(qq, off);
    }
    float m = s * (1.f / 512.f);
    float var = qq * (1.f / 512.f) - m * m;
    float r = rsqrtf(var + 1e-5f);
    float o[8];
#pragma unroll
    for (int j = 0; j < 8; ++j)
        o[j] = (v[j] - m) * r * g1[l * 8 + j] + b1[l * 8 + j];
    float4* op = (float4*)(lnout + base);
    op[0] = make_float4(o[0], o[1], o[2], o[3]);
    op[1] = make_float4(o[4], o[5], o[6], o[7]);
}

// ---------------------------------------------------------------------------
// Window mix: x_mid[p] = x[p] + sum_j sw[h][p][j]*ln[j] + sb. In-place on
// d_out (disjoint token partition; all 49 ln rows staged before any write).
// ---------------------------------------------------------------------------
__global__ __launch_bounds__(512) void mix_k(const float* __restrict__ xin,
                                             const float* __restrict__ lnb,
                                             const float* __restrict__ sw,
                                             const float* __restrict__ sb,
                                             float* __restrict__ outp) {
    __shared__ alignas(16) u16 raw[49 * 512];
    __shared__ int toks[49];
    const int tid = threadIdx.x;
    const int wid = blockIdx.x;
    const int b = wid / 81, rem = wid % 81;
    const int wy = rem / 9, wx = rem % 9;

    if (tid < 49) {
        int py = tid / 7, px = tid % 7;
        int y = wy * 7 + py - 4, x = wx * 7 + px - 4;  // PT=PL=4
        toks[tid] = ((unsigned)y < 56u && (unsigned)x < 56u)
                        ? (b * 3136 + y * 56 + x) : -1;
    }
    __syncthreads();

    for (int idx = tid; idx < 49 * 64; idx += 512) {
        int p = idx >> 6, uu = idx & 63;
        int tk = toks[p];
        uint4 w = make_uint4(0, 0, 0, 0);
        if (tk >= 0) {
            const float4* s0 = (const float4*)(lnb + (size_t)tk * 512 + uu * 8);
            float4 a = s0[0], bb = s0[1];
            w.x = pack2(a.x, a.y);  w.y = pack2(a.z, a.w);
            w.z = pack2(bb.x, bb.y); w.w = pack2(bb.z, bb.w);
        }
        *(uint4*)(raw + p * 512 + uu * 8) = w;
    }
    __syncthreads();

    const int c = tid;
    const int h = c >> 5;
    float lnv[49];
#pragma unroll
    for (int j = 0; j < 49; ++j) lnv[j] = bf2f(raw[j * 512 + c]);

    const size_t swbase = (size_t)h * 2401;
    for (int p = 0; p < 49; ++p) {
        int tk = toks[p];
        if (tk < 0) continue;
        float acc = 0.f;
#pragma unroll
        for (int j = 0; j < 49; ++j)
            acc += sw[swbase + p * 49 + j] * lnv[j];
        float o = acc + sb[h * 49 + p] + xin[(size_t)tk * 512 + c];
        outp[(size_t)tk * 512 + c] = o;
    }
}

// ---------------------------------------------------------------------------
// LN2 stats (mean, rstd) from x_mid fp32. 8 tokens/block.
// ---------------------------------------------------------------------------
__global__ __launch_bounds__(512) void stats_k(const float* __restrict__ xm,
                                               float2* __restrict__ st) {
    const int token = blockIdx.x * 8 + (threadIdx.x >> 6);
    const int l = threadIdx.x & 63;
    const size_t base = (size_t)token * 512 + l * 8;
    const float4* p = (const float4*)(xm + base);
    float4 a = p[0], b = p[1];
    float v[8] = {a.x, a.y, a.z, a.w, b.x, b.y, b.z, b.w};
    float s = 0.f, qq = 0.f;
#pragma unroll
    for (int j = 0; j < 8; ++j) { s += v[j]; qq += v[j] * v[j]; }
#pragma unroll
    for (int off = 1; off < 64; off <<= 1) {
        s += __shfl_xor(s, off); qq += __shfl_xor(qq, off);
    }
    if (l == 0) {
        float m = s * (1.f / 512.f);
        float var = qq * (1.f / 512.f) - m * m;
        st[token] = make_float2(m, rsqrtf(var + 1e-5f));
    }
}

// ---------------------------------------------------------------------------
// GEMM1: hid[bf16] = GELU(LN2(x_mid[f32]) @ W1t[bf16] + bb1), 128x128 tile,
// BK=64, 4 waves (2x2), T14 reg-prefetch, XCD-swizzled 1D grid. (unchanged)
// ---------------------------------------------------------------------------
__global__ __launch_bounds__(256) void gemm1_k(const float* __restrict__ A,
                                               const float2* __restrict__ stats,
                                               const float* __restrict__ G,
                                               const float* __restrict__ Bv,
                                               const u16* __restrict__ Wt,
                                               const float* __restrict__ bias,
                                               u16* __restrict__ Out, int row0) {
    constexpr int KD = 512, ND = 2048;
    __shared__ alignas(16) u16 As[128 * 64];
    __shared__ alignas(16) u16 Bs[128 * 64];
    const int tid = threadIdx.x;
    const int l = tid & 63, w = tid >> 6;
    const int wm = w >> 1, wn = w & 1;
    const int lr = l & 15, lk = l >> 4;

    const int wg = xcd_swz(blockIdx.x, gridDim.x);
    const int bm = wg >> 4, bn = wg & 15;

    int pr_[4], gc_[4];
    const float* Ap[4]; const u16* Bp[4];
    float2 st_[4];
#pragma unroll
    for (int i = 0; i < 4; ++i) {
        int q = tid + i * 256;
        int r = q >> 3, cc = q & 7;
        pr_[i] = r * 8 + (cc ^ (r & 7));
        gc_[i] = cc * 8;
        int arow = row0 + bm * 128 + r;
        Ap[i] = A + (size_t)arow * KD + cc * 8;
        Bp[i] = Wt + (size_t)(bn * 128 + r) * KD + cc * 8;
        st_[i] = stats[arow];
    }

    float4 raA[4][2]; uint4 rb4[4];
#pragma unroll
    for (int i = 0; i < 4; ++i) {
        raA[i][0] = *(const float4*)Ap[i];
        raA[i][1] = *(const float4*)(Ap[i] + 4);
        rb4[i] = *(const uint4*)Bp[i];
    }

    f32x4 acc[4][4] = {};

    for (int ks = 0; ks < KD; ks += 64) {
#pragma unroll
        for (int i = 0; i < 4; ++i) {
            float xv[8] = {raA[i][0].x, raA[i][0].y, raA[i][0].z, raA[i][0].w,
                           raA[i][1].x, raA[i][1].y, raA[i][1].z, raA[i][1].w};
            float o[8];
#pragma unroll
            for (int j = 0; j < 8; ++j) {
                float nv = (xv[j] - st_[i].x) * st_[i].y;
                o[j] = nv * G[ks + gc_[i] + j] + Bv[ks + gc_[i] + j];
            }
            uint4 wv;
            wv.x = pack2(o[0], o[1]); wv.y = pack2(o[2], o[3]);
            wv.z = pack2(o[4], o[5]); wv.w = pack2(o[6], o[7]);
            reinterpret_cast<uint4*>(As)[pr_[i]] = wv;
            reinterpret_cast<uint4*>(Bs)[pr_[i]] = rb4[i];
        }
        __syncthreads();
        if (ks + 64 < KD) {
#pragma unroll
            for (int i = 0; i < 4; ++i) {
                raA[i][0] = *(const float4*)(Ap[i] + ks + 64);
                raA[i][1] = *(const float4*)(Ap[i] + ks + 68);
                rb4[i] = *(const uint4*)(Bp[i] + ks + 64);
            }
        }
#pragma unroll
        for (int kk = 0; kk < 2; ++kk) {
            bf16x8 af[4], bfr[4];
#pragma unroll
            for (int f = 0; f < 4; ++f) {
                int ra = wm * 64 + f * 16 + lr;
                af[f] = *reinterpret_cast<const bf16x8*>(
                    As + ra * 64 + (((kk * 4 + lk) ^ (ra & 7)) * 8));
                int rb = wn * 64 + f * 16 + lr;
                bfr[f] = *reinterpret_cast<const bf16x8*>(
                    Bs + rb * 64 + (((kk * 4 + lk) ^ (rb & 7)) * 8));
            }
#pragma unroll
            for (int fi = 0; fi < 4; ++fi)
#pragma unroll
                for (int fj = 0; fj < 4; ++fj)
                    acc[fi][fj] = __builtin_amdgcn_mfma_f32_16x16x32_bf16(
                        af[fi], bfr[fj], acc[fi][fj], 0, 0, 0);
        }
        __syncthreads();
    }

#pragma unroll
    for (int fi = 0; fi < 4; ++fi) {
#pragma unroll
        for (int fj = 0; fj < 4; ++fj) {
#pragma unroll
            for (int rr = 0; rr < 4; ++rr) {
                int mrow = bm * 128 + wm * 64 + fi * 16 + lk * 4 + rr;
                int ncol = bn * 128 + wn * 64 + fj * 16 + lr;
                float v = acc[fi][fj][rr] + bias[ncol];
                float ge = 0.5f * v * (1.0f + erff(v * 0.70710678118654752f));
                Out[(size_t)mrow * ND + ncol] = f2bf(ge);
            }
        }
    }
}

// ---------------------------------------------------------------------------
// GEMM2: d_out[f32] += hid[bf16] @ W2t[bf16] + bb2. 128x128 tile, BK=64,
// 4 waves, T14 reg-prefetch, XCD-swizzled 1D grid.
// Epilogue: TWO-PHASE LDS C-tile (64x128 f32 = 32 KB fits staging LDS
// exactly), each phase: quadrant deposit -> barrier -> dense float4 RMW.
// ---------------------------------------------------------------------------
__global__ __launch_bounds__(256) void gemm2_k(const u16* __restrict__ A,
                                               const u16* __restrict__ Wt,
                                               const float* __restrict__ bias,
                                               float* __restrict__ Out, int row0) {
    constexpr int KD = 2048, ND = 512;
    __shared__ alignas(16) u16 smem[2 * 128 * 64];   // As | Bs, 32 KB total
    u16* As = smem;
    u16* Bs = smem + 128 * 64;
    const int tid = threadIdx.x;
    const int l = tid & 63, w = tid >> 6;
    const int wm = w >> 1, wn = w & 1;
    const int lr = l & 15, lk = l >> 4;

    const int wg = xcd_swz(blockIdx.x, gridDim.x);
    const int bm = wg >> 2, bn = wg & 3;

    int pr_[4];
    const u16* Ap[4]; const u16* Bp[4];
#pragma unroll
    for (int i = 0; i < 4; ++i) {
        int q = tid + i * 256;
        int r = q >> 3, cc = q & 7;
        pr_[i] = r * 8 + (cc ^ (r & 7));
        Ap[i] = A + (size_t)(bm * 128 + r) * KD + cc * 8;
        Bp[i] = Wt + (size_t)(bn * 128 + r) * KD + cc * 8;
    }

    uint4 ra4[4], rb4[4];
#pragma unroll
    for (int i = 0; i < 4; ++i) {
        ra4[i] = *(const uint4*)Ap[i];
        rb4[i] = *(const uint4*)Bp[i];
    }

    f32x4 acc[4][4] = {};

    for (int ks = 0; ks < KD; ks += 64) {
#pragma unroll
        for (int i = 0; i < 4; ++i) {
            reinterpret_cast<uint4*>(As)[pr_[i]] = ra4[i];
            reinterpret_cast<uint4*>(Bs)[pr_[i]] = rb4[i];
        }
        __syncthreads();
        if (ks + 64 < KD) {
#pragma unroll
            for (int i = 0; i < 4; ++i) {
                ra4[i] = *(const uint4*)(Ap[i] + ks + 64);
                rb4[i] = *(const uint4*)(Bp[i] + ks + 64);
            }
        }
#pragma unroll
        for (int kk = 0; kk < 2; ++kk) {
            bf16x8 af[4], bfr[4];
#pragma unroll
            for (int f = 0; f < 4; ++f) {
                int ra = wm * 64 + f * 16 + lr;
                af[f] = *reinterpret_cast<const bf16x8*>(
                    As + ra * 64 + (((kk * 4 + lk) ^ (ra & 7)) * 8));
                int rb = wn * 64 + f * 16 + lr;
                bfr[f] = *reinterpret_cast<const bf16x8*>(
                    Bs + rb * 64 + (((kk * 4 + lk) ^ (rb & 7)) * 8));
            }
#pragma unroll
            for (int fi = 0; fi < 4; ++fi)
#pragma unroll
                for (int fj = 0; fj < 4; ++fj)
                    acc[fi][fj] = __builtin_amdgcn_mfma_f32_16x16x32_bf16(
                        af[fi], bfr[fj], acc[fi][fj], 0, 0, 0);
        }
        __syncthreads();
    }

    // ---- two-phase epilogue: 64x128 f32 half-tile in the 32 KB staging LDS
    float* Cs = (float*)smem;   // 64*128 f32 = 32768 B, fits exactly
#pragma unroll
    for (int half = 0; half < 2; ++half) {
        if (wm == half) {
#pragma unroll
            for (int fi = 0; fi < 4; ++fi) {
#pragma unroll
                for (int fj = 0; fj < 4; ++fj) {
                    int col = wn * 64 + fj * 16 + lr;
                    float bcol = bias[bn * 128 + col];
#pragma unroll
                    for (int rr = 0; rr < 4; ++rr) {
                        int row = fi * 16 + lk * 4 + rr;   // 0..63 within half
                        Cs[row * 128 + col] = acc[fi][fj][rr] + bcol;
                    }
                }
            }
        }
        __syncthreads();
#pragma unroll
        for (int it = 0; it < 4; ++it) {
            int row = it * 16 + (tid >> 4);
            int cb = (tid & 15) * 8;
            float4 c0 = *(const float4*)(Cs + row * 128 + cb);
            float4 c1 = *(const float4*)(Cs + row * 128 + cb + 4);
            size_t go = (size_t)(row0 + bm * 128 + half * 64 + row) * ND
                        + bn * 128 + cb;
            float4 r0 = *(const float4*)(Out + go);
            float4 r1 = *(const float4*)(Out + go + 4);
            r0.x += c0.x; r0.y += c0.y; r0.z += c0.z; r0.w += c0.w;
            r1.x += c1.x; r1.y += c1.y; r1.z += c1.z; r1.w += c1.w;
            *(float4*)(Out + go) = r0;
            *(float4*)(Out + go + 4) = r1;
        }
        __syncthreads();
    }
}

// ---------------------------------------------------------------------------
extern "C" void kernel_launch(void* const* d_in, const int* in_sizes, int n_in,
                              void* d_out, int out_size, void* d_ws, size_t ws_size,
                              hipStream_t stream) {
    const float* x   = (const float*)d_in[0];
    const float* g1  = (const float*)d_in[1];
    const float* b1  = (const float*)d_in[2];
    const float* sw  = (const float*)d_in[3];
    const float* sb  = (const float*)d_in[4];
    const float* g2  = (const float*)d_in[5];
    const float* b2  = (const float*)d_in[6];
    const float* w1  = (const float*)d_in[7];
    const float* bb1 = (const float*)d_in[8];
    const float* w2  = (const float*)d_in[9];
    const float* bb2 = (const float*)d_in[10];
    float* out = (float*)d_out;

    char* ws = (char*)d_ws;
    float2* stats = (float2*)ws;                          // 802816 B
    u16* w1t = (u16*)(ws + 802816);                       // [2048][512]  2 MB
    u16* w2t = (u16*)(ws + 802816 + 2097152);             // [512][2048]  2 MB
    size_t hid_off = 802816 + 2u * 2097152;               // 4,997,120
    u16* hid = (u16*)(ws + hid_off);                      // chunked [rows][2048]

    long avail = (long)ws_size - (long)hid_off;
    long maxT = avail / (128 * 2048 * 2);
    int chunkT = (int)(maxT < 1 ? 1 : (maxT > 784 ? 784 : maxT));

    transp_k<<<dim3(64, 16), 256, 0, stream>>>(w1, w1t, 512, 2048);
    transp_k<<<dim3(16, 64), 256, 0, stream>>>(w2, w2t, 2048, 512);
    ln_k<<<12544, 512, 0, stream>>>(x, g1, b1, out);
    mix_k<<<2592, 512, 0, stream>>>(x, out, sw, sb, out);
    stats_k<<<12544, 512, 0, stream>>>(out, stats);
    for (int t0 = 0; t0 < 784; t0 += chunkT) {
        int nt = (784 - t0) < chunkT ? (784 - t0) : chunkT;
        gemm1_k<<<nt * 16, 256, 0, stream>>>(
            out, stats, g2, b2, w1t, bb1, hid, t0 * 128);
        gemm2_k<<<nt * 4, 256, 0, stream>>>(
            hid, w2t, bb2, out, t0 * 128);
    }
}

// Round 9
// 1386.210 us; speedup vs baseline: 2.4766x; 1.8052x over previous
//
#include <hip/hip_runtime.h>
#include <cstdint>

using u16 = unsigned short;
using u32 = unsigned int;

typedef __bf16 bf16x8 __attribute__((ext_vector_type(8)));
typedef float f32x4 __attribute__((ext_vector_type(4)));

__device__ __forceinline__ float bf2f(u16 u) {
    u32 v = ((u32)u) << 16; float f; __builtin_memcpy(&f, &v, 4); return f;
}
__device__ __forceinline__ u16 f2bf(float f) {
    u32 u; __builtin_memcpy(&u, &f, 4);
    u32 r = (u + 0x7fffu + ((u >> 16) & 1u)) >> 16; return (u16)r;
}
__device__ __forceinline__ u32 pack2(float a, float b) {
    return (u32)f2bf(a) | ((u32)f2bf(b) << 16);
}
// bijective chunked XCD swizzle (m204)
__device__ __forceinline__ int xcd_swz(int orig, int nwg) {
    int q = nwg >> 3, r8 = nwg & 7;
    int xcd = orig & 7, slot = orig >> 3;
    return (xcd < r8 ? xcd * (q + 1) : r8 * (q + 1) + (xcd - r8) * q) + slot;
}
// async global->LDS, 16B/lane; LDS dest wave-uniform base + lane*16
__device__ __forceinline__ void async_cp16(const u16* g, u16* l) {
    __builtin_amdgcn_global_load_lds(
        (const __attribute__((address_space(1))) void*)g,
        (__attribute__((address_space(3))) void*)l, 16, 0, 0);
}

// ---------------------------------------------------------------------------
// weight transpose: w [R][C] fp32 -> wt [C][R] bf16
// ---------------------------------------------------------------------------
__global__ __launch_bounds__(256) void transp_k(const float* __restrict__ in,
                                                u16* __restrict__ outp,
                                                int R, int C) {
    __shared__ alignas(16) u16 t[32][33];
    int tx = threadIdx.x & 31, ty = threadIdx.x >> 5;
    int bx = blockIdx.x * 32, by = blockIdx.y * 32;
#pragma unroll
    for (int i = 0; i < 4; ++i)
        t[ty + i * 8][tx] = f2bf(in[(size_t)(by + ty + i * 8) * C + bx + tx]);
    __syncthreads();
#pragma unroll
    for (int i = 0; i < 4; ++i)
        outp[(size_t)(bx + ty + i * 8) * R + by + tx] = t[tx][ty + i * 8];
}

// ---------------------------------------------------------------------------
// LN1: fp32 in -> fp32 ln(x)*g1+b1 into d_out (temp). 8 tokens/block.
// ---------------------------------------------------------------------------
__global__ __launch_bounds__(512) void ln_k(const float* __restrict__ xin,
                                            const float* __restrict__ g1,
                                            const float* __restrict__ b1,
                                            float* __restrict__ lnout) {
    const int token = blockIdx.x * 8 + (threadIdx.x >> 6);
    const int l = threadIdx.x & 63;
    const size_t base = (size_t)token * 512 + l * 8;
    const float4* p = (const float4*)(xin + base);
    float4 a = p[0], b = p[1];
    float v[8] = {a.x, a.y, a.z, a.w, b.x, b.y, b.z, b.w};
    float s = 0.f, qq = 0.f;
#pragma unroll
    for (int j = 0; j < 8; ++j) { s += v[j]; qq += v[j] * v[j]; }
#pragma unroll
    for (int off = 1; off < 64; off <<= 1) {
        s += __shfl_xor(s, off); qq += __shfl_xor(qq, off);
    }
    float m = s * (1.f / 512.f);
    float var = qq * (1.f / 512.f) - m * m;
    float r = rsqrtf(var + 1e-5f);
    float o[8];
#pragma unroll
    for (int j = 0; j < 8; ++j)
        o[j] = (v[j] - m) * r * g1[l * 8 + j] + b1[l * 8 + j];
    float4* op = (float4*)(lnout + base);
    op[0] = make_float4(o[0], o[1], o[2], o[3]);
    op[1] = make_float4(o[4], o[5], o[6], o[7]);
}

// ---------------------------------------------------------------------------
// Window mix: x_mid[p] = x[p] + sum_j sw[h][p][j]*ln[j] + sb. In-place on
// d_out (disjoint token partition; all 49 ln rows staged before any write).
// ---------------------------------------------------------------------------
__global__ __launch_bounds__(512) void mix_k(const float* __restrict__ xin,
                                             const float* __restrict__ lnb,
                                             const float* __restrict__ sw,
                                             const float* __restrict__ sb,
                                             float* __restrict__ outp) {
    __shared__ alignas(16) u16 raw[49 * 512];
    __shared__ int toks[49];
    const int tid = threadIdx.x;
    const int wid = blockIdx.x;
    const int b = wid / 81, rem = wid % 81;
    const int wy = rem / 9, wx = rem % 9;

    if (tid < 49) {
        int py = tid / 7, px = tid % 7;
        int y = wy * 7 + py - 4, x = wx * 7 + px - 4;  // PT=PL=4
        toks[tid] = ((unsigned)y < 56u && (unsigned)x < 56u)
                        ? (b * 3136 + y * 56 + x) : -1;
    }
    __syncthreads();

    for (int idx = tid; idx < 49 * 64; idx += 512) {
        int p = idx >> 6, uu = idx & 63;
        int tk = toks[p];
        uint4 w = make_uint4(0, 0, 0, 0);
        if (tk >= 0) {
            const float4* s0 = (const float4*)(lnb + (size_t)tk * 512 + uu * 8);
            float4 a = s0[0], bb = s0[1];
            w.x = pack2(a.x, a.y);  w.y = pack2(a.z, a.w);
            w.z = pack2(bb.x, bb.y); w.w = pack2(bb.z, bb.w);
        }
        *(uint4*)(raw + p * 512 + uu * 8) = w;
    }
    __syncthreads();

    const int c = tid;
    const int h = c >> 5;
    float lnv[49];
#pragma unroll
    for (int j = 0; j < 49; ++j) lnv[j] = bf2f(raw[j * 512 + c]);

    const size_t swbase = (size_t)h * 2401;
    for (int p = 0; p < 49; ++p) {
        int tk = toks[p];
        if (tk < 0) continue;
        float acc = 0.f;
#pragma unroll
        for (int j = 0; j < 49; ++j)
            acc += sw[swbase + p * 49 + j] * lnv[j];
        float o = acc + sb[h * 49 + p] + xin[(size_t)tk * 512 + c];
        outp[(size_t)tk * 512 + c] = o;
    }
}

// ---------------------------------------------------------------------------
// LN2 for a row-chunk: reads x_mid f32 rows [row0, row0+nrows), writes bf16
// chunk-local ln2c[r][512]. 8 tokens/block.
// ---------------------------------------------------------------------------
__global__ __launch_bounds__(512) void ln2_k(const float* __restrict__ xm,
                                             const float* __restrict__ g2,
                                             const float* __restrict__ b2,
                                             u16* __restrict__ outc, int row0) {
    const int lrow = blockIdx.x * 8 + (threadIdx.x >> 6);
    const int l = threadIdx.x & 63;
    const size_t gbase = (size_t)(row0 + lrow) * 512 + l * 8;
    const float4* p = (const float4*)(xm + gbase);
    float4 a = p[0], b = p[1];
    float v[8] = {a.x, a.y, a.z, a.w, b.x, b.y, b.z, b.w};
    float s = 0.f, qq = 0.f;
#pragma unroll
    for (int j = 0; j < 8; ++j) { s += v[j]; qq += v[j] * v[j]; }
#pragma unroll
    for (int off = 1; off < 64; off <<= 1) {
        s += __shfl_xor(s, off); qq += __shfl_xor(qq, off);
    }
    float m = s * (1.f / 512.f);
    float var = qq * (1.f / 512.f) - m * m;
    float r = rsqrtf(var + 1e-5f);
    float o[8];
#pragma unroll
    for (int j = 0; j < 8; ++j)
        o[j] = (v[j] - m) * r * g2[l * 8 + j] + b2[l * 8 + j];
    uint4 w;
    w.x = pack2(o[0], o[1]); w.y = pack2(o[2], o[3]);
    w.z = pack2(o[4], o[5]); w.w = pack2(o[6], o[7]);
    *(uint4*)(outc + (size_t)lrow * 512 + l * 8) = w;
}

// ---------------------------------------------------------------------------
// MFMA GEMM, m97 structure: 128x128 tile, BK=64, 4 waves (2x2),
// global_load_lds width-16 staging (pre-swizzled source chunk c^(r&7),
// linear LDS dest), vmcnt(0)+barrier per K-step, XCD-swizzled 1D grid.
// Both A and Wt are bf16 [rows][KD], K-contiguous.
// EPI==0: bias+GELU -> Out bf16 (chunk-local rows)
// EPI==1: two-phase LDS C-tile + dense float4 residual RMW on f32 Out
// ---------------------------------------------------------------------------
template <int KD, int ND, int EPI>
__global__ __launch_bounds__(256) void gemm_k(const u16* __restrict__ A,
                                              const u16* __restrict__ Wt,
                                              const float* __restrict__ bias,
                                              void* __restrict__ Out, int row0) {
    __shared__ alignas(16) u16 smem[2 * 128 * 64];   // As | Bs, 32 KB
    u16* As = smem;
    u16* Bs = smem + 128 * 64;
    const int tid = threadIdx.x;
    const int l = tid & 63, w = tid >> 6;
    const int wm = w >> 1, wn = w & 1;
    const int lr = l & 15, lk = l >> 4;

    const int wg = xcd_swz(blockIdx.x, gridDim.x);
    constexpr int NTN = ND / 128;
    const int bm = wg / NTN, bn = wg % NTN;   // consecutive wg share bm

    // staging addresses: physical slot s holds logical chunk pc^(rr&7)
    const u16* gA[4]; const u16* gB[4]; u16* lA[4]; u16* lB[4];
#pragma unroll
    for (int i = 0; i < 4; ++i) {
        int s = (w * 4 + i) * 64 + l;
        int rr = s >> 3, pc = s & 7, cc = pc ^ (rr & 7);
        gA[i] = A  + (size_t)(bm * 128 + rr) * KD + cc * 8;
        gB[i] = Wt + (size_t)(bn * 128 + rr) * KD + cc * 8;
        lA[i] = As + (w * 4 + i) * 512;   // wave-uniform base
        lB[i] = Bs + (w * 4 + i) * 512;
    }

    f32x4 acc[4][4] = {};

    for (int ks = 0; ks < KD; ks += 64) {
#pragma unroll
        for (int i = 0; i < 4; ++i) async_cp16(gA[i], lA[i]);
#pragma unroll
        for (int i = 0; i < 4; ++i) async_cp16(gB[i], lB[i]);
#pragma unroll
        for (int i = 0; i < 4; ++i) { gA[i] += 64; gB[i] += 64; }
        asm volatile("s_waitcnt vmcnt(0)" ::: "memory");
        __syncthreads();
#pragma unroll
        for (int kk = 0; kk < 2; ++kk) {
            bf16x8 af[4], bfr[4];
#pragma unroll
            for (int f = 0; f < 4; ++f) {
                int ra = wm * 64 + f * 16 + lr;
                af[f] = *reinterpret_cast<const bf16x8*>(
                    As + ra * 64 + (((kk * 4 + lk) ^ (ra & 7)) * 8));
                int rb = wn * 64 + f * 16 + lr;
                bfr[f] = *reinterpret_cast<const bf16x8*>(
                    Bs + rb * 64 + (((kk * 4 + lk) ^ (rb & 7)) * 8));
            }
#pragma unroll
            for (int fi = 0; fi < 4; ++fi)
#pragma unroll
                for (int fj = 0; fj < 4; ++fj)
                    acc[fi][fj] = __builtin_amdgcn_mfma_f32_16x16x32_bf16(
                        af[fi], bfr[fj], acc[fi][fj], 0, 0, 0);
        }
        __syncthreads();
    }

    if (EPI == 0) {
        // bias + GELU -> bf16 Out (chunk-local). D row=(lane>>4)*4+reg, col=lane&15
        u16* O16 = (u16*)Out;
#pragma unroll
        for (int fi = 0; fi < 4; ++fi) {
#pragma unroll
            for (int fj = 0; fj < 4; ++fj) {
#pragma unroll
                for (int rr = 0; rr < 4; ++rr) {
                    int mrow = bm * 128 + wm * 64 + fi * 16 + lk * 4 + rr;
                    int ncol = bn * 128 + wn * 64 + fj * 16 + lr;
                    float v = acc[fi][fj][rr] + bias[ncol];
                    float ge = 0.5f * v * (1.0f + erff(v * 0.70710678118654752f));
                    O16[(size_t)mrow * ND + ncol] = f2bf(ge);
                }
            }
        }
    } else {
        // two-phase 64x128 f32 LDS C-tile (32 KB) + dense float4 residual RMW
        float* Of = (float*)Out;
        float* Cs = (float*)smem;
#pragma unroll
        for (int half = 0; half < 2; ++half) {
            if (wm == half) {
#pragma unroll
                for (int fi = 0; fi < 4; ++fi) {
#pragma unroll
                    for (int fj = 0; fj < 4; ++fj) {
                        int col = wn * 64 + fj * 16 + lr;
                        float bcol = bias[bn * 128 + col];
#pragma unroll
                        for (int rr = 0; rr < 4; ++rr) {
                            int row = fi * 16 + lk * 4 + rr;
                            Cs[row * 128 + col] = acc[fi][fj][rr] + bcol;
                        }
                    }
                }
            }
            __syncthreads();
#pragma unroll
            for (int it = 0; it < 4; ++it) {
                int row = it * 16 + (tid >> 4);
                int cb = (tid & 15) * 8;
                float4 c0 = *(const float4*)(Cs + row * 128 + cb);
                float4 c1 = *(const float4*)(Cs + row * 128 + cb + 4);
                size_t go = (size_t)(row0 + bm * 128 + half * 64 + row) * ND
                            + bn * 128 + cb;
                float4 r0 = *(const float4*)(Of + go);
                float4 r1 = *(const float4*)(Of + go + 4);
                r0.x += c0.x; r0.y += c0.y; r0.z += c0.z; r0.w += c0.w;
                r1.x += c1.x; r1.y += c1.y; r1.z += c1.z; r1.w += c1.w;
                *(float4*)(Of + go) = r0;
                *(float4*)(Of + go + 4) = r1;
            }
            __syncthreads();
        }
    }
}

// ---------------------------------------------------------------------------
extern "C" void kernel_launch(void* const* d_in, const int* in_sizes, int n_in,
                              void* d_out, int out_size, void* d_ws, size_t ws_size,
                              hipStream_t stream) {
    const float* x   = (const float*)d_in[0];
    const float* g1  = (const float*)d_in[1];
    const float* b1  = (const float*)d_in[2];
    const float* sw  = (const float*)d_in[3];
    const float* sb  = (const float*)d_in[4];
    const float* g2  = (const float*)d_in[5];
    const float* b2  = (const float*)d_in[6];
    const float* w1  = (const float*)d_in[7];
    const float* bb1 = (const float*)d_in[8];
    const float* w2  = (const float*)d_in[9];
    const float* bb2 = (const float*)d_in[10];
    float* out = (float*)d_out;

    char* ws = (char*)d_ws;
    u16* w1t = (u16*)ws;                                  // [2048][512]  2 MB
    u16* w2t = (u16*)(ws + 2097152);                      // [512][2048]  2 MB
    size_t cbase = 2u * 2097152;                          // chunk area

    // per 128-row tile: ln2c 128*512*2 = 131072 B, hid 128*2048*2 = 524288 B
    long avail = (long)ws_size - (long)cbase;
    long maxT = avail / 655360;
    int chunkT = (int)(maxT < 1 ? 1 : (maxT > 784 ? 784 : maxT));
    u16* ln2c = (u16*)(ws + cbase);
    u16* hid  = (u16*)(ws + cbase + (size_t)chunkT * 131072);

    transp_k<<<dim3(64, 16), 256, 0, stream>>>(w1, w1t, 512, 2048);
    transp_k<<<dim3(16, 64), 256, 0, stream>>>(w2, w2t, 2048, 512);
    ln_k<<<12544, 512, 0, stream>>>(x, g1, b1, out);
    mix_k<<<2592, 512, 0, stream>>>(x, out, sw, sb, out);
    for (int t0 = 0; t0 < 784; t0 += chunkT) {
        int nt = (784 - t0) < chunkT ? (784 - t0) : chunkT;
        ln2_k<<<nt * 16, 512, 0, stream>>>(out, g2, b2, ln2c, t0 * 128);
        gemm_k<512, 2048, 0><<<nt * 16, 256, 0, stream>>>(
            ln2c, w1t, bb1, hid, 0);
        gemm_k<2048, 512, 1><<<nt * 4, 256, 0, stream>>>(
            hid, w2t, bb2, out, t0 * 128);
    }
}

// Round 10
// 1144.581 us; speedup vs baseline: 2.9995x; 1.2111x over previous
//
#include <hip/hip_runtime.h>
#include <cstdint>

using u16 = unsigned short;
using u32 = unsigned int;

typedef __bf16 bf16x8 __attribute__((ext_vector_type(8)));
typedef float f32x4 __attribute__((ext_vector_type(4)));

__device__ __forceinline__ float bf2f(u16 u) {
    u32 v = ((u32)u) << 16; float f; __builtin_memcpy(&f, &v, 4); return f;
}
__device__ __forceinline__ u16 f2bf(float f) {
    u32 u; __builtin_memcpy(&u, &f, 4);
    u32 r = (u + 0x7fffu + ((u >> 16) & 1u)) >> 16; return (u16)r;
}
__device__ __forceinline__ u32 pack2(float a, float b) {
    return (u32)f2bf(a) | ((u32)f2bf(b) << 16);
}
// bijective chunked XCD swizzle (m204)
__device__ __forceinline__ int xcd_swz(int orig, int nwg) {
    int q = nwg >> 3, r8 = nwg & 7;
    int xcd = orig & 7, slot = orig >> 3;
    return (xcd < r8 ? xcd * (q + 1) : r8 * (q + 1) + (xcd - r8) * q) + slot;
}
// async global->LDS, 16B/lane; LDS dest wave-uniform base + lane*16
__device__ __forceinline__ void async_cp16(const u16* g, u16* l) {
    __builtin_amdgcn_global_load_lds(
        (const __attribute__((address_space(1))) void*)g,
        (__attribute__((address_space(3))) void*)l, 16, 0, 0);
}

// ---------------------------------------------------------------------------
// weight transpose: w [R][C] fp32 -> wt [C][R] bf16
// ---------------------------------------------------------------------------
__global__ __launch_bounds__(256) void transp_k(const float* __restrict__ in,
                                                u16* __restrict__ outp,
                                                int R, int C) {
    __shared__ alignas(16) u16 t[32][33];
    int tx = threadIdx.x & 31, ty = threadIdx.x >> 5;
    int bx = blockIdx.x * 32, by = blockIdx.y * 32;
#pragma unroll
    for (int i = 0; i < 4; ++i)
        t[ty + i * 8][tx] = f2bf(in[(size_t)(by + ty + i * 8) * C + bx + tx]);
    __syncthreads();
#pragma unroll
    for (int i = 0; i < 4; ++i)
        outp[(size_t)(bx + ty + i * 8) * R + by + tx] = t[tx][ty + i * 8];
}

// ---------------------------------------------------------------------------
// Fused LN1 + window mix: per window block,
//   phase A: stage ln1(x)*g1+b1 (f32-exact stats) as bf16 into LDS (zeros at
//            padded positions — matches reference pad-after-LN),
//   phase B: sw staged in LDS per 4-position chunk, per-thread 49-FMA mix,
//            + residual read of x, write x_mid -> d_out.
// ---------------------------------------------------------------------------
__global__ __launch_bounds__(512, 2) void spatial_k(const float* __restrict__ xin,
                                                    const float* __restrict__ g1,
                                                    const float* __restrict__ b1,
                                                    const float* __restrict__ sw,
                                                    const float* __restrict__ sb,
                                                    float* __restrict__ outp) {
    __shared__ alignas(16) u16 raw[49 * 512];        // 50176 B (ln bf16)
    __shared__ float swl[16 * 4 * 49];               // 12544 B (sw chunk)
    __shared__ int toks[49];                         //   196 B
    const int tid = threadIdx.x;
    const int wid = blockIdx.x;
    const int b = wid / 81, rem = wid % 81;
    const int wy = rem / 9, wx = rem % 9;

    if (tid < 49) {
        int py = tid / 7, px = tid % 7;
        int y = wy * 7 + py - 4, x = wx * 7 + px - 4;  // PT=PL=4
        toks[tid] = ((unsigned)y < 56u && (unsigned)x < 56u)
                        ? (b * 3136 + y * 56 + x) : -1;
    }
    __syncthreads();

    // ---- phase A: LN1 per position, one wave per position (stride 8)
    const int l = tid & 63, wvi = tid >> 6;
    float g1v[8], b1v[8];
#pragma unroll
    for (int j = 0; j < 8; ++j) { g1v[j] = g1[l * 8 + j]; b1v[j] = b1[l * 8 + j]; }
    for (int p = wvi; p < 49; p += 8) {
        int tk = toks[p];
        uint4 w = make_uint4(0, 0, 0, 0);
        if (tk >= 0) {
            const float4* pp = (const float4*)(xin + (size_t)tk * 512 + l * 8);
            float4 a = pp[0], bb = pp[1];
            float v[8] = {a.x, a.y, a.z, a.w, bb.x, bb.y, bb.z, bb.w};
            float s = 0.f, qq = 0.f;
#pragma unroll
            for (int j = 0; j < 8; ++j) { s += v[j]; qq += v[j] * v[j]; }
#pragma unroll
            for (int off = 1; off < 64; off <<= 1) {
                s += __shfl_xor(s, off); qq += __shfl_xor(qq, off);
            }
            float m = s * (1.f / 512.f);
            float var = qq * (1.f / 512.f) - m * m;
            float r = rsqrtf(var + 1e-5f);
            float o[8];
#pragma unroll
            for (int j = 0; j < 8; ++j)
                o[j] = (v[j] - m) * r * g1v[j] + b1v[j];
            w.x = pack2(o[0], o[1]); w.y = pack2(o[2], o[3]);
            w.z = pack2(o[4], o[5]); w.w = pack2(o[6], o[7]);
        }
        *(uint4*)(raw + p * 512 + l * 8) = w;
    }
    __syncthreads();

    // ---- phase B: chunked sw staging + mix
    const int c = tid;
    const int h = c >> 5;
    float lnv[49];
#pragma unroll
    for (int j = 0; j < 49; ++j) lnv[j] = bf2f(raw[j * 512 + c]);

    for (int pc0 = 0; pc0 < 49; pc0 += 4) {
        const int pc = (49 - pc0) < 4 ? (49 - pc0) : 4;
        // stage sw[h][pc0+p][j] for all h, p<pc (coalesced over j)
        for (int idx = tid; idx < 16 * pc * 49; idx += 512) {
            int hh = idx / (pc * 49), r2 = idx % (pc * 49);
            int p2 = r2 / 49, j2 = r2 % 49;
            swl[hh * 196 + p2 * 49 + j2] = sw[(size_t)hh * 2401 + (pc0 + p2) * 49 + j2];
        }
        __syncthreads();
        for (int p = 0; p < pc; ++p) {
            int tk = toks[pc0 + p];
            if (tk >= 0) {
                const float* swp = swl + h * 196 + p * 49;
                float acc = 0.f;
#pragma unroll
                for (int j = 0; j < 49; ++j)
                    acc += swp[j] * lnv[j];
                float o = acc + sb[h * 49 + pc0 + p] + xin[(size_t)tk * 512 + c];
                outp[(size_t)tk * 512 + c] = o;
            }
        }
        __syncthreads();
    }
}

// ---------------------------------------------------------------------------
// LN2 for a row-chunk: reads x_mid f32 rows [row0, row0+nrows), writes bf16
// chunk-local ln2c[r][512]. 8 tokens/block.
// ---------------------------------------------------------------------------
__global__ __launch_bounds__(512) void ln2_k(const float* __restrict__ xm,
                                             const float* __restrict__ g2,
                                             const float* __restrict__ b2,
                                             u16* __restrict__ outc, int row0) {
    const int lrow = blockIdx.x * 8 + (threadIdx.x >> 6);
    const int l = threadIdx.x & 63;
    const size_t gbase = (size_t)(row0 + lrow) * 512 + l * 8;
    const float4* p = (const float4*)(xm + gbase);
    float4 a = p[0], b = p[1];
    float v[8] = {a.x, a.y, a.z, a.w, b.x, b.y, b.z, b.w};
    float s = 0.f, qq = 0.f;
#pragma unroll
    for (int j = 0; j < 8; ++j) { s += v[j]; qq += v[j] * v[j]; }
#pragma unroll
    for (int off = 1; off < 64; off <<= 1) {
        s += __shfl_xor(s, off); qq += __shfl_xor(qq, off);
    }
    float m = s * (1.f / 512.f);
    float var = qq * (1.f / 512.f) - m * m;
    float r = rsqrtf(var + 1e-5f);
    float o[8];
#pragma unroll
    for (int j = 0; j < 8; ++j)
        o[j] = (v[j] - m) * r * g2[l * 8 + j] + b2[l * 8 + j];
    uint4 w;
    w.x = pack2(o[0], o[1]); w.y = pack2(o[2], o[3]);
    w.z = pack2(o[4], o[5]); w.w = pack2(o[6], o[7]);
    *(uint4*)(outc + (size_t)lrow * 512 + l * 8) = w;
}

// ---------------------------------------------------------------------------
// MFMA GEMM, m97 structure: 128x128 tile, BK=64, 4 waves (2x2),
// global_load_lds width-16 staging (pre-swizzled source chunk c^(r&7),
// linear LDS dest), vmcnt(0)+barrier per K-step, XCD-swizzled 1D grid.
// EPI==0: bias+GELU -> Out bf16 (chunk-local rows)
// EPI==1: two-phase LDS C-tile + dense float4 residual RMW on f32 Out
// ---------------------------------------------------------------------------
template <int KD, int ND, int EPI>
__global__ __launch_bounds__(256) void gemm_k(const u16* __restrict__ A,
                                              const u16* __restrict__ Wt,
                                              const float* __restrict__ bias,
                                              void* __restrict__ Out, int row0) {
    __shared__ alignas(16) u16 smem[2 * 128 * 64];   // As | Bs, 32 KB
    u16* As = smem;
    u16* Bs = smem + 128 * 64;
    const int tid = threadIdx.x;
    const int l = tid & 63, w = tid >> 6;
    const int wm = w >> 1, wn = w & 1;
    const int lr = l & 15, lk = l >> 4;

    const int wg = xcd_swz(blockIdx.x, gridDim.x);
    constexpr int NTN = ND / 128;
    const int bm = wg / NTN, bn = wg % NTN;   // consecutive wg share bm

    // staging addresses: physical slot s holds logical chunk pc^(rr&7)
    const u16* gA[4]; const u16* gB[4]; u16* lA[4]; u16* lB[4];
#pragma unroll
    for (int i = 0; i < 4; ++i) {
        int s = (w * 4 + i) * 64 + l;
        int rr = s >> 3, pc = s & 7, cc = pc ^ (rr & 7);
        gA[i] = A  + (size_t)(bm * 128 + rr) * KD + cc * 8;
        gB[i] = Wt + (size_t)(bn * 128 + rr) * KD + cc * 8;
        lA[i] = As + (w * 4 + i) * 512;   // wave-uniform base
        lB[i] = Bs + (w * 4 + i) * 512;
    }

    f32x4 acc[4][4] = {};

    for (int ks = 0; ks < KD; ks += 64) {
#pragma unroll
        for (int i = 0; i < 4; ++i) async_cp16(gA[i], lA[i]);
#pragma unroll
        for (int i = 0; i < 4; ++i) async_cp16(gB[i], lB[i]);
#pragma unroll
        for (int i = 0; i < 4; ++i) { gA[i] += 64; gB[i] += 64; }
        asm volatile("s_waitcnt vmcnt(0)" ::: "memory");
        __syncthreads();
#pragma unroll
        for (int kk = 0; kk < 2; ++kk) {
            bf16x8 af[4], bfr[4];
#pragma unroll
            for (int f = 0; f < 4; ++f) {
                int ra = wm * 64 + f * 16 + lr;
                af[f] = *reinterpret_cast<const bf16x8*>(
                    As + ra * 64 + (((kk * 4 + lk) ^ (ra & 7)) * 8));
                int rb = wn * 64 + f * 16 + lr;
                bfr[f] = *reinterpret_cast<const bf16x8*>(
                    Bs + rb * 64 + (((kk * 4 + lk) ^ (rb & 7)) * 8));
            }
#pragma unroll
            for (int fi = 0; fi < 4; ++fi)
#pragma unroll
                for (int fj = 0; fj < 4; ++fj)
                    acc[fi][fj] = __builtin_amdgcn_mfma_f32_16x16x32_bf16(
                        af[fi], bfr[fj], acc[fi][fj], 0, 0, 0);
        }
        __syncthreads();
    }

    if (EPI == 0) {
        // bias + GELU -> bf16 Out (chunk-local). D row=(lane>>4)*4+reg, col=lane&15
        u16* O16 = (u16*)Out;
#pragma unroll
        for (int fi = 0; fi < 4; ++fi) {
#pragma unroll
            for (int fj = 0; fj < 4; ++fj) {
#pragma unroll
                for (int rr = 0; rr < 4; ++rr) {
                    int mrow = bm * 128 + wm * 64 + fi * 16 + lk * 4 + rr;
                    int ncol = bn * 128 + wn * 64 + fj * 16 + lr;
                    float v = acc[fi][fj][rr] + bias[ncol];
                    float ge = 0.5f * v * (1.0f + erff(v * 0.70710678118654752f));
                    O16[(size_t)mrow * ND + ncol] = f2bf(ge);
                }
            }
        }
    } else {
        // two-phase 64x128 f32 LDS C-tile (32 KB) + dense float4 residual RMW
        float* Of = (float*)Out;
        float* Cs = (float*)smem;
#pragma unroll
        for (int half = 0; half < 2; ++half) {
            if (wm == half) {
#pragma unroll
                for (int fi = 0; fi < 4; ++fi) {
#pragma unroll
                    for (int fj = 0; fj < 4; ++fj) {
                        int col = wn * 64 + fj * 16 + lr;
                        float bcol = bias[bn * 128 + col];
#pragma unroll
                        for (int rr = 0; rr < 4; ++rr) {
                            int row = fi * 16 + lk * 4 + rr;
                            Cs[row * 128 + col] = acc[fi][fj][rr] + bcol;
                        }
                    }
                }
            }
            __syncthreads();
#pragma unroll
            for (int it = 0; it < 4; ++it) {
                int row = it * 16 + (tid >> 4);
                int cb = (tid & 15) * 8;
                float4 c0 = *(const float4*)(Cs + row * 128 + cb);
                float4 c1 = *(const float4*)(Cs + row * 128 + cb + 4);
                size_t go = (size_t)(row0 + bm * 128 + half * 64 + row) * ND
                            + bn * 128 + cb;
                float4 r0 = *(const float4*)(Of + go);
                float4 r1 = *(const float4*)(Of + go + 4);
                r0.x += c0.x; r0.y += c0.y; r0.z += c0.z; r0.w += c0.w;
                r1.x += c1.x; r1.y += c1.y; r1.z += c1.z; r1.w += c1.w;
                *(float4*)(Of + go) = r0;
                *(float4*)(Of + go + 4) = r1;
            }
            __syncthreads();
        }
    }
}

// ---------------------------------------------------------------------------
extern "C" void kernel_launch(void* const* d_in, const int* in_sizes, int n_in,
                              void* d_out, int out_size, void* d_ws, size_t ws_size,
                              hipStream_t stream) {
    const float* x   = (const float*)d_in[0];
    const float* g1  = (const float*)d_in[1];
    const float* b1  = (const float*)d_in[2];
    const float* sw  = (const float*)d_in[3];
    const float* sb  = (const float*)d_in[4];
    const float* g2  = (const float*)d_in[5];
    const float* b2  = (const float*)d_in[6];
    const float* w1  = (const float*)d_in[7];
    const float* bb1 = (const float*)d_in[8];
    const float* w2  = (const float*)d_in[9];
    const float* bb2 = (const float*)d_in[10];
    float* out = (float*)d_out;

    char* ws = (char*)d_ws;
    u16* w1t = (u16*)ws;                                  // [2048][512]  2 MB
    u16* w2t = (u16*)(ws + 2097152);                      // [512][2048]  2 MB
    size_t cbase = 2u * 2097152;                          // chunk area

    // per 128-row tile: ln2c 128*512*2 = 131072 B, hid 128*2048*2 = 524288 B
    long avail = (long)ws_size - (long)cbase;
    long maxT = avail / 655360;
    int chunkT = (int)(maxT < 1 ? 1 : (maxT > 784 ? 784 : maxT));
    u16* ln2c = (u16*)(ws + cbase);
    u16* hid  = (u16*)(ws + cbase + (size_t)chunkT * 131072);

    transp_k<<<dim3(64, 16), 256, 0, stream>>>(w1, w1t, 512, 2048);
    transp_k<<<dim3(16, 64), 256, 0, stream>>>(w2, w2t, 2048, 512);
    spatial_k<<<2592, 512, 0, stream>>>(x, g1, b1, sw, sb, out);
    for (int t0 = 0; t0 < 784; t0 += chunkT) {
        int nt = (784 - t0) < chunkT ? (784 - t0) : chunkT;
        ln2_k<<<nt * 16, 512, 0, stream>>>(out, g2, b2, ln2c, t0 * 128);
        gemm_k<512, 2048, 0><<<nt * 16, 256, 0, stream>>>(
            ln2c, w1t, bb1, hid, 0);
        gemm_k<2048, 512, 1><<<nt * 4, 256, 0, stream>>>(
            hid, w2t, bb2, out, t0 * 128);
    }
}